// Round 4
// baseline (156.788 us; speedup 1.0000x reference)
//
#include <hip/hip_runtime.h>

// Problem constants (from reference): B=32, N=2048, S=64, D=1024, fp32.
constexpr int B = 32;
constexpr int N = 2048;
constexpr int S = 64;
constexpr int D = 1024;
constexpr int ROW4 = D / 4;                  // 256 float4 per row
constexpr long TOTAL4 = (long)B * N * ROW4;  // 16,777,216 float4
constexpr int BLOCK = 256;
constexpr int GRID  = 2048;                  // 8 blocks/CU
constexpr int ITERS = (int)(TOTAL4 / ((long)GRID * BLOCK)); // exactly 32

typedef float f4 __attribute__((ext_vector_type(4)));

// Kernel 1: dead-simple streaming copy — the shape that hits the measured
// 6.29 TB/s ceiling. No LDS, no branch, no NT hints, no index math.
__global__ __launch_bounds__(BLOCK) void pure_copy(const f4* __restrict__ src,
                                                   f4* __restrict__ dst) {
    const long stride = (long)GRID * BLOCK;
    long gid = (long)blockIdx.x * BLOCK + threadIdx.x;
#pragma unroll 8
    for (int it = 0; it < ITERS; ++it, gid += stride) {
        dst[gid] = src[gid];
    }
}

// Kernel 2: fixup. One block per (b, s). Only the last-occurrence winner for
// a given index writes (numpy sequential-set semantics). Reads the ORIGINAL
// state row (gather source — the copy kernel didn't touch state), interpolates,
// overwrites the out row. 256 threads x float4 == exactly one D=1024 row.
__global__ __launch_bounds__(BLOCK) void fixup(const f4* __restrict__ state,
                                               const f4* __restrict__ substate,
                                               const float* __restrict__ probs,
                                               const int* __restrict__ idx,
                                               f4* __restrict__ out) {
    const int b = blockIdx.x >> 6;           // batch
    const int s = blockIdx.x & (S - 1);      // selection slot
    __shared__ int sidx[S];
    if (threadIdx.x < S) sidx[threadIdx.x] = idx[b * S + threadIdx.x];
    __syncthreads();
    const int n = sidx[s];
    // last-duplicate-wins: bail if any later slot targets the same row
    for (int t = s + 1; t < S; ++t)
        if (sidx[t] == n) return;            // block-uniform branch
    const float p = probs[b * S + s];
    const long rowBase = ((long)b * N + n) * ROW4;
    const long subBase = ((long)b * S + s) * ROW4;
    const int e = threadIdx.x;
    f4 g = state[rowBase + e];
    f4 v = substate[subBase + e];
    out[rowBase + e] = (1.0f - p) * g + p * v;
}

extern "C" void kernel_launch(void* const* d_in, const int* in_sizes, int n_in,
                              void* d_out, int out_size, void* d_ws, size_t ws_size,
                              hipStream_t stream) {
    const f4*    state    = (const f4*)d_in[0];
    const f4*    substate = (const f4*)d_in[1];
    const int*   idx      = (const int*)d_in[2];
    const float* probs    = (const float*)d_in[3];
    f4*          out      = (f4*)d_out;

    pure_copy<<<GRID, BLOCK, 0, stream>>>(state, out);
    // same-stream ordering gives the WAW ordering fixup needs
    fixup<<<B * S, BLOCK, 0, stream>>>(state, substate, probs, idx, out);
}

// Round 5
// 106.096 us; speedup vs baseline: 1.4778x; 1.4778x over previous
//
#include <hip/hip_runtime.h>

// Problem constants (from reference): B=32, N=2048, S=64, D=1024, fp32.
constexpr int B = 32;
constexpr int N = 2048;
constexpr int S = 64;
constexpr int D = 1024;
constexpr int ROW4 = D / 4;                 // 256 float4 per row
constexpr int BLOCK = 256;
constexpr int CHUNKS_PER_BATCH = 64;        // blocks per batch
constexpr int ROWS_PER_CHUNK = N / CHUNKS_PER_BATCH;   // 32 rows
constexpr int F4_PER_CHUNK = ROWS_PER_CHUNK * ROW4;    // 8192
constexpr int ITERS = ROWS_PER_CHUNK;       // 1 row (256 f4) per block-iter
constexpr int GRID = B * CHUNKS_PER_BATCH;  // 2048 blocks = 8/CU on 256 CUs

typedef float f4 __attribute__((ext_vector_type(4)));

// Single fused kernel, fully branchless inner loop.
// Each block owns 32 consecutive rows of one batch. LDS winner map gives
// last-duplicate-wins selection; non-selected rows use p=0 (o == g exactly,
// substate read clamped to row 0 -> L1-hot broadcast, ~0 HBM traffic).
__global__ __launch_bounds__(BLOCK) void fused_update(
    const f4* __restrict__ state, const f4* __restrict__ substate,
    const float* __restrict__ probs, const int* __restrict__ idx,
    f4* __restrict__ out) {
    __shared__ int win[N];                  // 8 KB
    const int b = blockIdx.x >> 6;          // batch
    const int chunk = blockIdx.x & 63;

    for (int i = threadIdx.x; i < N; i += BLOCK) win[i] = 0;
    __syncthreads();
    if (threadIdx.x < S)
        atomicMax(&win[idx[b * S + threadIdx.x]], threadIdx.x + 1);
    __syncthreads();

    const int rowStart = chunk * ROWS_PER_CHUNK;
    const int e = threadIdx.x;              // f4 index within row (constant)
    long gid = (long)b * (N * ROW4) + (long)rowStart * ROW4 + e;
#pragma unroll 8
    for (int it = 0; it < ITERS; ++it, gid += ROW4) {
        int w = win[rowStart + it];         // uniform LDS broadcast
        int sel = w > 0;
        int bs = (b << 6) + (sel ? w - 1 : 0);   // clamped -> always valid
        float praw = probs[bs];             // always-valid load (B*S floats)
        float p = sel ? praw : 0.0f;        // p=0 => o == g exactly
        f4 g = __builtin_nontemporal_load(&state[gid]);
        f4 v = substate[(long)bs * ROW4 + e];    // non-sel: L1-hot row-0
        f4 o = (1.0f - p) * g + p * v;
        __builtin_nontemporal_store(o, &out[gid]);
    }
}

extern "C" void kernel_launch(void* const* d_in, const int* in_sizes, int n_in,
                              void* d_out, int out_size, void* d_ws, size_t ws_size,
                              hipStream_t stream) {
    const f4*    state    = (const f4*)d_in[0];
    const f4*    substate = (const f4*)d_in[1];
    const int*   idx      = (const int*)d_in[2];
    const float* probs    = (const float*)d_in[3];
    f4*          out      = (f4*)d_out;

    fused_update<<<GRID, BLOCK, 0, stream>>>(state, substate, probs, idx, out);
}

// Round 6
// 100.139 us; speedup vs baseline: 1.5657x; 1.0595x over previous
//
#include <hip/hip_runtime.h>

// Problem constants (from reference): B=32, N=2048, S=64, D=1024, fp32.
constexpr int B = 32;
constexpr int N = 2048;
constexpr int S = 64;
constexpr int D = 1024;
constexpr int ROW4 = D / 4;                 // 256 float4 per row
constexpr int BLOCK = 256;
constexpr int CHUNKS_PER_BATCH = 64;        // blocks per batch
constexpr int ROWS_PER_CHUNK = N / CHUNKS_PER_BATCH;   // 32 rows
constexpr int ITERS = ROWS_PER_CHUNK;       // 1 row (256 f4) per block-iter
constexpr int GRID = B * CHUNKS_PER_BATCH;  // 2048 blocks = 8/CU on 256 CUs

typedef float f4 __attribute__((ext_vector_type(4)));

// Single fused kernel, branchless inner loop.
// A/B delta vs R5: state is loaded through the NORMAL cache path (L3 can
// serve it across replays — R4 showed ~half of state stays L3-resident),
// while out keeps the nontemporal store (bypasses L2/L3, prevents the
// write-stream from evicting state; R4 showed plain stores cost 2x).
__global__ __launch_bounds__(BLOCK) void fused_update(
    const f4* __restrict__ state, const f4* __restrict__ substate,
    const float* __restrict__ probs, const int* __restrict__ idx,
    f4* __restrict__ out) {
    __shared__ int win[N];                  // 8 KB
    const int b = blockIdx.x >> 6;          // batch
    const int chunk = blockIdx.x & 63;

    for (int i = threadIdx.x; i < N; i += BLOCK) win[i] = 0;
    __syncthreads();
    if (threadIdx.x < S)
        atomicMax(&win[idx[b * S + threadIdx.x]], threadIdx.x + 1);
    __syncthreads();

    const int rowStart = chunk * ROWS_PER_CHUNK;
    const int e = threadIdx.x;              // f4 index within row (constant)
    long gid = (long)b * (N * ROW4) + (long)rowStart * ROW4 + e;
#pragma unroll 8
    for (int it = 0; it < ITERS; ++it, gid += ROW4) {
        int w = win[rowStart + it];         // uniform LDS broadcast
        int sel = w > 0;
        int bs = (b << 6) + (sel ? w - 1 : 0);   // clamped -> always valid
        float praw = probs[bs];             // always-valid load (B*S floats)
        float p = sel ? praw : 0.0f;        // p=0 => o == g exactly
        f4 g = state[gid];                  // PLAIN load: let L3 serve it
        f4 v = substate[(long)bs * ROW4 + e];    // non-sel: L1-hot row-0
        f4 o = (1.0f - p) * g + p * v;
        __builtin_nontemporal_store(o, &out[gid]);
    }
}

extern "C" void kernel_launch(void* const* d_in, const int* in_sizes, int n_in,
                              void* d_out, int out_size, void* d_ws, size_t ws_size,
                              hipStream_t stream) {
    const f4*    state    = (const f4*)d_in[0];
    const f4*    substate = (const f4*)d_in[1];
    const int*   idx      = (const int*)d_in[2];
    const float* probs    = (const float*)d_in[3];
    f4*          out      = (f4*)d_out;

    fused_update<<<GRID, BLOCK, 0, stream>>>(state, substate, probs, idx, out);
}

// Round 7
// 99.168 us; speedup vs baseline: 1.5810x; 1.0098x over previous
//
#include <hip/hip_runtime.h>

// Problem constants (from reference): B=32, N=2048, S=64, D=1024, fp32.
constexpr int B = 32;
constexpr int N = 2048;
constexpr int S = 64;
constexpr int D = 1024;
constexpr int ROW4 = D / 4;                 // 256 float4 per row
constexpr int BLOCK = 256;
constexpr int CHUNKS_PER_BATCH = 64;        // blocks per batch
constexpr int ROWS_PER_CHUNK = N / CHUNKS_PER_BATCH;   // 32 rows
constexpr int ITERS = ROWS_PER_CHUNK;       // 1 row (256 f4) per block-iter
constexpr int GRID = B * CHUNKS_PER_BATCH;  // 2048 blocks = 8/CU on 256 CUs

typedef float f4 __attribute__((ext_vector_type(4)));

// Single fused kernel, branchless inner loop.
// Cache-partitioning on the state read stream: rows with (row&3)==3 are
// nontemporal-loaded (never allocate in L3), the other 75% (192 MB) use the
// normal cache path and should fit/stay resident in the 256 MB L3 across
// graph replays (R6 showed 50% L3 hit at full 256 MB footprint — at-capacity
// thrash; shrinking the cached footprint should push its hit rate near 100%).
// out keeps the NT store (R4: plain stores through L2 cost 2x).
__global__ __launch_bounds__(BLOCK) void fused_update(
    const f4* __restrict__ state, const f4* __restrict__ substate,
    const float* __restrict__ probs, const int* __restrict__ idx,
    f4* __restrict__ out) {
    __shared__ int win[N];                  // 8 KB
    const int b = blockIdx.x >> 6;          // batch
    const int chunk = blockIdx.x & 63;

    for (int i = threadIdx.x; i < N; i += BLOCK) win[i] = 0;
    __syncthreads();
    if (threadIdx.x < S)
        atomicMax(&win[idx[b * S + threadIdx.x]], threadIdx.x + 1);
    __syncthreads();

    const int rowStart = chunk * ROWS_PER_CHUNK;   // multiple of 32
    const int e = threadIdx.x;              // f4 index within row (constant)
    long gid = (long)b * (N * ROW4) + (long)rowStart * ROW4 + e;
#pragma unroll 8
    for (int it = 0; it < ITERS; ++it, gid += ROW4) {
        int w = win[rowStart + it];         // uniform LDS broadcast
        int sel = w > 0;
        int bs = (b << 6) + (sel ? w - 1 : 0);   // clamped -> always valid
        float praw = probs[bs];             // always-valid load (B*S floats)
        float p = sel ? praw : 0.0f;        // p=0 => o == g exactly
        // (it & 3) is compile-time static per unrolled slot (rowStart % 8 == 0)
        f4 g = ((it & 3) == 3) ? __builtin_nontemporal_load(&state[gid])
                               : state[gid];
        f4 v = substate[(long)bs * ROW4 + e];    // non-sel: L1-hot row-0
        f4 o = (1.0f - p) * g + p * v;
        __builtin_nontemporal_store(o, &out[gid]);
    }
}

extern "C" void kernel_launch(void* const* d_in, const int* in_sizes, int n_in,
                              void* d_out, int out_size, void* d_ws, size_t ws_size,
                              hipStream_t stream) {
    const f4*    state    = (const f4*)d_in[0];
    const f4*    substate = (const f4*)d_in[1];
    const int*   idx      = (const int*)d_in[2];
    const float* probs    = (const float*)d_in[3];
    f4*          out      = (f4*)d_out;

    fused_update<<<GRID, BLOCK, 0, stream>>>(state, substate, probs, idx, out);
}

// Round 8
// 93.046 us; speedup vs baseline: 1.6851x; 1.0658x over previous
//
#include <hip/hip_runtime.h>

// Problem constants (from reference): B=32, N=2048, S=64, D=1024, fp32.
constexpr int B = 32;
constexpr int N = 2048;
constexpr int S = 64;
constexpr int D = 1024;
constexpr int ROW4 = D / 4;                 // 256 float4 per row
constexpr int BLOCK = 256;
constexpr int CHUNKS_PER_BATCH = 64;
constexpr int ROWS_PER_CHUNK = N / CHUNKS_PER_BATCH;   // 32 rows
constexpr int ITERS = ROWS_PER_CHUNK;       // 32 row-iters per block
constexpr int GRID = B * CHUNKS_PER_BATCH;  // 2048 blocks = 8/CU

typedef float f4 __attribute__((ext_vector_type(4)));

// Kernel 1: pure streaming copy, zero per-iteration logic.
// Plain loads (L3 serves ~50% across replays — R6/R7), NT stores (R4: 2x).
// Block-chunked contiguous 128 KB per block, matching the R6 shape that ran
// best. This isolates whether R6's per-iter LDS/probs/substate loads (1.5x
// VMEM instruction count) were throttling the stream.
__global__ __launch_bounds__(BLOCK) void copy_nt(const f4* __restrict__ src,
                                                 f4* __restrict__ dst) {
    long gid = (long)blockIdx.x * (ITERS * BLOCK) + threadIdx.x;
#pragma unroll 8
    for (int it = 0; it < ITERS; ++it, gid += BLOCK) {
        __builtin_nontemporal_store(src[gid], &dst[gid]);
    }
}

// Kernel 2: fixup — one block per (b, s); only the last-occurrence winner for
// a duplicated index writes (numpy sequential-set semantics). Reads ORIGINAL
// state (copy didn't modify it), interpolates, overwrites the out row.
// 256 threads x float4 == exactly one D=1024 row. ~24 MB total traffic.
__global__ __launch_bounds__(BLOCK) void fixup(const f4* __restrict__ state,
                                               const f4* __restrict__ substate,
                                               const float* __restrict__ probs,
                                               const int* __restrict__ idx,
                                               f4* __restrict__ out) {
    const int b = blockIdx.x >> 6;           // batch
    const int s = blockIdx.x & (S - 1);      // selection slot
    __shared__ int sidx[S];
    if (threadIdx.x < S) sidx[threadIdx.x] = idx[b * S + threadIdx.x];
    __syncthreads();
    const int n = sidx[s];
    // last-duplicate-wins: bail if any later slot targets the same row
    for (int t = s + 1; t < S; ++t)
        if (sidx[t] == n) return;            // block-uniform branch
    const float p = probs[b * S + s];
    const long rowBase = ((long)b * N + n) * ROW4;
    const long subBase = ((long)b * S + s) * ROW4;
    const int e = threadIdx.x;
    f4 g = state[rowBase + e];
    f4 v = substate[subBase + e];
    __builtin_nontemporal_store((1.0f - p) * g + p * v, &out[rowBase + e]);
}

extern "C" void kernel_launch(void* const* d_in, const int* in_sizes, int n_in,
                              void* d_out, int out_size, void* d_ws, size_t ws_size,
                              hipStream_t stream) {
    const f4*    state    = (const f4*)d_in[0];
    const f4*    substate = (const f4*)d_in[1];
    const int*   idx      = (const int*)d_in[2];
    const float* probs    = (const float*)d_in[3];
    f4*          out      = (f4*)d_out;

    copy_nt<<<GRID, BLOCK, 0, stream>>>(state, out);
    // same-stream ordering provides the WAW ordering fixup requires
    fixup<<<B * S, BLOCK, 0, stream>>>(state, substate, probs, idx, out);
}

// Round 9
// 90.991 us; speedup vs baseline: 1.7231x; 1.0226x over previous
//
#include <hip/hip_runtime.h>

// Problem constants (from reference): B=32, N=2048, S=64, D=1024, fp32.
constexpr int B = 32;
constexpr int N = 2048;
constexpr int S = 64;
constexpr int D = 1024;
constexpr int ROW4 = D / 4;                 // 256 float4 per row
constexpr int BLOCK = 256;                  // one row per block-wide op
constexpr int CHUNKS_PER_BATCH = 64;
constexpr int ROWS_PER_CHUNK = N / CHUNKS_PER_BATCH;   // 32 rows = 128 KB
constexpr int GRID = B * CHUNKS_PER_BATCH;  // 2048 blocks = 8/CU

typedef float f4 __attribute__((ext_vector_type(4)));

// Single dispatch: pure-copy loop (R8's exact inner body) + in-block fixup.
// Prologue builds a 32-entry winner map covering ONLY this block's rows
// (last-duplicate-wins via atomicMax over s+1). The copy loop has zero
// per-iteration logic (R6 showed that logic costs ~6%). After __syncthreads
// (compiler drains vmcnt before s_barrier -> WAW overwrite is ordered), the
// block rewrites its selected rows (~1 per block on average).
// Plain state loads (L3 serves ~50%, R6/R7); NT stores (R4: 2x).
__global__ __launch_bounds__(BLOCK) void copy_fix(
    const f4* __restrict__ state, const f4* __restrict__ substate,
    const float* __restrict__ probs, const int* __restrict__ idx,
    f4* __restrict__ out) {
    __shared__ int win[ROWS_PER_CHUNK];
    const int b = blockIdx.x >> 6;
    const int chunk = blockIdx.x & 63;
    const int rowStart = chunk * ROWS_PER_CHUNK;

    if (threadIdx.x < ROWS_PER_CHUNK) win[threadIdx.x] = 0;
    __syncthreads();
    if (threadIdx.x < S) {
        int r = idx[b * S + threadIdx.x] - rowStart;
        if ((unsigned)r < (unsigned)ROWS_PER_CHUNK)
            atomicMax(&win[r], (int)threadIdx.x + 1);
    }

    // pure streaming copy of my 128 KB chunk — identical to R8's copy_nt body
    long gid = (long)blockIdx.x * (ROWS_PER_CHUNK * ROW4) + threadIdx.x;
#pragma unroll 8
    for (int it = 0; it < ROWS_PER_CHUNK; ++it, gid += BLOCK)
        __builtin_nontemporal_store(state[gid], &out[gid]);

    __syncthreads();  // win[] visible; copy stores drained (vmcnt(0) at barrier)

    // fixup: rewrite selected rows of my chunk (block-uniform branches)
    const long chunkBase = (long)blockIdx.x * (ROWS_PER_CHUNK * ROW4);
    for (int r = 0; r < ROWS_PER_CHUNK; ++r) {
        int w = win[r];
        if (w > 0) {
            int s = w - 1;
            float p = probs[(b << 6) + s];
            long rowBase = chunkBase + (long)r * ROW4;
            f4 g = state[rowBase + threadIdx.x];
            f4 v = substate[((long)(b << 6) + s) * ROW4 + threadIdx.x];
            __builtin_nontemporal_store((1.0f - p) * g + p * v,
                                        &out[rowBase + threadIdx.x]);
        }
    }
}

extern "C" void kernel_launch(void* const* d_in, const int* in_sizes, int n_in,
                              void* d_out, int out_size, void* d_ws, size_t ws_size,
                              hipStream_t stream) {
    const f4*    state    = (const f4*)d_in[0];
    const f4*    substate = (const f4*)d_in[1];
    const int*   idx      = (const int*)d_in[2];
    const float* probs    = (const float*)d_in[3];
    f4*          out      = (f4*)d_out;

    copy_fix<<<GRID, BLOCK, 0, stream>>>(state, substate, probs, idx, out);
}

// Round 10
// 87.753 us; speedup vs baseline: 1.7867x; 1.0369x over previous
//
#include <hip/hip_runtime.h>

// Problem constants (from reference): B=32, N=2048, S=64, D=1024, fp32.
constexpr int B = 32;
constexpr int N = 2048;
constexpr int S = 64;
constexpr int D = 1024;
constexpr int ROW4 = D / 4;                 // 256 float4 per row
constexpr int BLOCK = 256;                  // one row per block-wide op
constexpr int CHUNKS_PER_BATCH = 64;
constexpr int ROWS_PER_CHUNK = N / CHUNKS_PER_BATCH;   // 32 rows = 128 KB
constexpr int GRID = B * CHUNKS_PER_BATCH;  // 2048 blocks = 8/CU

typedef float f4 __attribute__((ext_vector_type(4)));

// R9 + explicit 8-deep register staging in the copy loop.
// R9's VGPR_Count=28 shows the compiler kept only ~4 float4 in flight;
// explicit load-8-then-store-8 batches force 8 outstanding loads per wave
// (fills the vmcnt queue, hides load latency behind the NT store burst).
// Everything else identical to R9: plain loads (L3 ~50%), NT stores (R4: 2x),
// in-block winner map + post-barrier fixup.
__global__ __launch_bounds__(BLOCK) void copy_fix(
    const f4* __restrict__ state, const f4* __restrict__ substate,
    const float* __restrict__ probs, const int* __restrict__ idx,
    f4* __restrict__ out) {
    __shared__ int win[ROWS_PER_CHUNK];
    const int b = blockIdx.x >> 6;
    const int chunk = blockIdx.x & 63;
    const int rowStart = chunk * ROWS_PER_CHUNK;

    if (threadIdx.x < ROWS_PER_CHUNK) win[threadIdx.x] = 0;
    __syncthreads();
    if (threadIdx.x < S) {
        int r = idx[b * S + threadIdx.x] - rowStart;
        if ((unsigned)r < (unsigned)ROWS_PER_CHUNK)
            atomicMax(&win[r], (int)threadIdx.x + 1);
    }

    // streaming copy: 4 macro-iters x (load 8 rows -> NT-store 8 rows)
    long gid = (long)blockIdx.x * (ROWS_PER_CHUNK * ROW4) + threadIdx.x;
#pragma unroll
    for (int mi = 0; mi < ROWS_PER_CHUNK / 8; ++mi) {
        f4 r[8];                            // fully static indexing
#pragma unroll
        for (int j = 0; j < 8; ++j) r[j] = state[gid + (long)j * BLOCK];
#pragma unroll
        for (int j = 0; j < 8; ++j)
            __builtin_nontemporal_store(r[j], &out[gid + (long)j * BLOCK]);
        gid += 8L * BLOCK;
    }

    __syncthreads();  // win[] visible; copy stores drained (vmcnt(0) at barrier)

    // fixup: rewrite selected rows of my chunk (block-uniform branches)
    const long chunkBase = (long)blockIdx.x * (ROWS_PER_CHUNK * ROW4);
    for (int r = 0; r < ROWS_PER_CHUNK; ++r) {
        int w = win[r];
        if (w > 0) {
            int s = w - 1;
            float p = probs[(b << 6) + s];
            long rowBase = chunkBase + (long)r * ROW4;
            f4 g = state[rowBase + threadIdx.x];
            f4 v = substate[((long)(b << 6) + s) * ROW4 + threadIdx.x];
            __builtin_nontemporal_store((1.0f - p) * g + p * v,
                                        &out[rowBase + threadIdx.x]);
        }
    }
}

extern "C" void kernel_launch(void* const* d_in, const int* in_sizes, int n_in,
                              void* d_out, int out_size, void* d_ws, size_t ws_size,
                              hipStream_t stream) {
    const f4*    state    = (const f4*)d_in[0];
    const f4*    substate = (const f4*)d_in[1];
    const int*   idx      = (const int*)d_in[2];
    const float* probs    = (const float*)d_in[3];
    f4*          out      = (f4*)d_out;

    copy_fix<<<GRID, BLOCK, 0, stream>>>(state, substate, probs, idx, out);
}